// Round 2
// baseline (234.058 us; speedup 1.0000x reference)
//
#include <hip/hip_runtime.h>
#include <hip/hip_bf16.h>
#include <stdint.h>

// CrissCrossAttention, MI355X gfx950.
// out = 2 * row-attention (column branch collapses exactly onto row branch).
// Pipeline: cvt x->bf16 | transpose W->bf16 | fused QKV GEMM | per-(b,h,r) MFMA
//           attention | GEMM(+bias) -> fp32 out.
// r8: gemm256 K-loop rewritten 4 phases -> 2 windows per K-tile (split by
//     M-half, both kk halves per window). Halves barrier count (2/tile) and
//     doubles MFMA per inter-barrier window (32). r7 measured 1500 cyc/phase
//     vs ~250 pipe floor -> stall-dominated; barrier/wait amortization is the
//     lever. vmcnt stays counted (2 at W0, 4 at W1), never 0 in-loop.

typedef __bf16 bf16_t;
typedef __bf16 bf16x4v __attribute__((ext_vector_type(4)));
typedef __bf16 bf16x8 __attribute__((ext_vector_type(8)));
typedef float  f32x4  __attribute__((ext_vector_type(4)));

#define GLD16(gp, lp)                                                                  \
  __builtin_amdgcn_global_load_lds((__attribute__((address_space(1))) const void*)(gp),\
                                   (__attribute__((address_space(3))) void*)(lp),      \
                                   16, 0, 0)

__device__ __forceinline__ float  bf2f(bf16_t x) { return (float)x; }
__device__ __forceinline__ bf16_t f2bf(float x)  { return (bf16_t)x; }

// ---------------------------------------------------------------------------
// fp32 -> bf16 conversion, float4 loads.
// ---------------------------------------------------------------------------
__global__ __launch_bounds__(256) void cvt_x(const float* __restrict__ X,
                                             bf16_t* __restrict__ Y, int n4)
{
  int i = blockIdx.x * blockDim.x + threadIdx.x;
  if (i < n4) {
    float4 v = ((const float4*)X)[i];
    bf16x4v o;
    o[0] = f2bf(v.x); o[1] = f2bf(v.y); o[2] = f2bf(v.z); o[3] = f2bf(v.w);
    ((bf16x4v*)Y)[i] = o;
  }
}

// ---------------------------------------------------------------------------
// Weight transpose + cast: WT[n][k] = (bf16)W[k][n], 512x512, z selects matrix.
// ---------------------------------------------------------------------------
__global__ void wt_kernel(const float* __restrict__ Wq, const float* __restrict__ Wk,
                          const float* __restrict__ Wv, const float* __restrict__ Wo,
                          bf16_t* __restrict__ WT)
{
  __shared__ bf16_t tile[32][33];
  const int mat = blockIdx.z;
  const float* W = (mat == 0) ? Wq : (mat == 1) ? Wk : (mat == 2) ? Wv : Wo;
  bf16_t* dst = WT + (size_t)mat * 262144;
  const int tx = threadIdx.x, ty = threadIdx.y;          // 32 x 8
  const int x0 = blockIdx.x * 32, y0 = blockIdx.y * 32;
#pragma unroll
  for (int i = 0; i < 32; i += 8)
    tile[ty + i][tx] = f2bf(W[(size_t)(y0 + ty + i) * 512 + x0 + tx]);
  __syncthreads();
#pragma unroll
  for (int i = 0; i < 32; i += 8)
    dst[(size_t)(x0 + ty + i) * 512 + y0 + tx] = tile[tx][ty + i];
}

// ---------------------------------------------------------------------------
// GEMM: C[M,Nd] = A[M,512] @ BT[Nd,512]^T (+bias), bf16 in, fp32 acc.
// 256x256 tile, 512 threads = 8 waves (2M x 4N), BK=64, K=512 -> 8 K-tiles.
// LDS 128KB: double-buffered A[256][64] + B[256][64], XOR-swizzled rows
//   (logical (row,seg16B) lives at byte row*128 + (seg*16 ^ ((row&7)<<4));
//    global_load_lds dest stays linear, source address pre-permuted - rule 21).
// Per K-tile: 2 windows (W0 = M-half 0, W1 = M-half 1), 32 MFMA each.
//   W0: 16 ds_read_b128 (A-ih0 + all B, both kk) | GLD B0..B3 of tile t+1
//   W1:  8 ds_read_b128 (A-ih1)                  | GLD A0,A2,A1,A3 of t+1
// Counted waits: vmcnt(2) at W0 (oldest-6 = B0..3+A0+A2), vmcnt(4) at W1
// (A1,A3; 4 new B's stay in flight). Never vmcnt(0) in the loop. Last tile
// prefetches junk (stays inside workspace, never read).
// XCD swizzle (proven r5): each XCD owns a contiguous m-band, n fastest.
// ---------------------------------------------------------------------------
template <bool STORE_F32>
__global__ __launch_bounds__(512, 2) void gemm256(
    const bf16_t* __restrict__ A,
    const bf16_t* __restrict__ BT,
    void* __restrict__ Cp,
    const float* __restrict__ bias,
    int Nd)
{
  __shared__ __align__(16) bf16_t smem[65536];   // 128 KB
  bf16_t* const sA = smem;            // [2][16384] = dbuf x 256 rows x 64
  bf16_t* const sB = smem + 32768;    // [2][16384]

  const int tid  = threadIdx.x;
  const int lane = tid & 63, w = tid >> 6;
  const int quad = lane >> 4, r16 = lane & 15;
  const int wr = w >> 2, wc = w & 3;             // wave grid 2 x 4
  const int wm = wr * 128, wn = wc * 64;

  // XCD-aware remap (8 XCDs, round-robin dispatch). gridDim.y = 128 m-tiles.
  const int G = gridDim.x;
  const int l = blockIdx.y * G + blockIdx.x;
  const int xcd = l & 7, slot = l >> 3;
  const int mb = xcd * (gridDim.y >> 3) + slot / G;
  const int nb = slot % G;
  const int m0 = mb * 256, n0 = nb * 256;

  // staging: call c stages rows [c*64, c*64+64); thread t -> row=t>>3,
  // 16B seg = (t&7) ^ (row&7)  (inverse of the read-side XOR swizzle).
  const int srow = tid >> 3;
  const int sseg = (tid & 7) ^ (srow & 7);
  const bf16_t* Ag = A  + (size_t)(m0 + srow) * 512 + sseg * 8;
  const bf16_t* Bg = BT + (size_t)(n0 + srow) * 512 + sseg * 8;
  const bf16_t *AgC[4], *BgC[4];
#pragma unroll
  for (int c = 0; c < 4; ++c) {
    AgC[c] = Ag + (size_t)c * 32768;             // 64 rows * 512
    BgC[c] = Bg + (size_t)c * 32768;
  }
  const int sdst = w * 512;                      // per-wave 1KB chunk (elems)

  // prologue: tile 0 -> buf 0. Order matters: oldest 6 must be B0..3,A0,A2.
  GLD16(BgC[0], sB + sdst);
  GLD16(BgC[1], sB + 4096  + sdst);
  GLD16(BgC[2], sB + 8192  + sdst);
  GLD16(BgC[3], sB + 12288 + sdst);
  GLD16(AgC[0], sA + sdst);
  GLD16(AgC[2], sA + 8192  + sdst);
  GLD16(AgC[1], sA + 4096  + sdst);
  GLD16(AgC[3], sA + 12288 + sdst);

  f32x4 acc[8][4] = {};

  const int xsw   = (r16 & 7) << 4;              // read-side XOR swizzle
  const int koff0 = (quad * 16) ^ xsw;           // kk=0 within-row byte
  const int koff1 = (64 + quad * 16) ^ xsw;      // kk=1

#pragma unroll
  for (int t = 0; t < 8; ++t) {
    const int p = t & 1, pn = p ^ 1;
    const int kn = (t + 1) * 64;                 // next tile K offset (elems)
    const char* sAp = (const char*)(sA + p * 16384);
    const char* sBp = (const char*)(sB + p * 16384);
    bf16_t* const dA = sA + pn * 16384 + sdst;
    bf16_t* const dB = sB + pn * 16384 + sdst;
    bf16x8 a0[4], a1[4], b0[4], b1[4];

    // ---- W0: M-half 0, both kk. Needs B0..3 + A0,A2 -> keep 2 outstanding.
    asm volatile("s_waitcnt vmcnt(2)" ::: "memory");
    __builtin_amdgcn_s_barrier();
    asm volatile("" ::: "memory");
#pragma unroll
    for (int i = 0; i < 4; ++i) {
      a0[i] = *(const bf16x8*)(sAp + (size_t)(wm + i * 16 + r16) * 128 + koff0);
      a1[i] = *(const bf16x8*)(sAp + (size_t)(wm + i * 16 + r16) * 128 + koff1);
    }
#pragma unroll
    for (int j = 0; j < 4; ++j) {
      b0[j] = *(const bf16x8*)(sBp + (size_t)(wn + j * 16 + r16) * 128 + koff0);
      b1[j] = *(const bf16x8*)(sBp + (size_t)(wn + j * 16 + r16) * 128 + koff1);
    }
    GLD16(BgC[0] + kn, dB);
    GLD16(BgC[1] + kn, dB + 4096);
    GLD16(BgC[2] + kn, dB + 8192);
    GLD16(BgC[3] + kn, dB + 12288);
    __builtin_amdgcn_s_setprio(1);
#pragma unroll
    for (int i = 0; i < 4; ++i)
#pragma unroll
      for (int j = 0; j < 4; ++j)
        acc[i][j] = __builtin_amdgcn_mfma_f32_16x16x32_bf16(a0[i], b0[j], acc[i][j], 0, 0, 0);
#pragma unroll
    for (int i = 0; i < 4; ++i)
#pragma unroll
      for (int j = 0; j < 4; ++j)
        acc[i][j] = __builtin_amdgcn_mfma_f32_16x16x32_bf16(a1[i], b1[j], acc[i][j], 0, 0, 0);
    __builtin_amdgcn_s_setprio(0);

    // ---- W1: M-half 1 (B reused from regs). Needs A1,A3; 4 new B's in flight.
    asm volatile("s_waitcnt vmcnt(4)" ::: "memory");
    __builtin_amdgcn_s_barrier();
    asm volatile("" ::: "memory");
#pragma unroll
    for (int i = 0; i < 4; ++i) {
      a0[i] = *(const bf16x8*)(sAp + (size_t)(wm + 64 + i * 16 + r16) * 128 + koff0);
      a1[i] = *(const bf16x8*)(sAp + (size_t)(wm + 64 + i * 16 + r16) * 128 + koff1);
    }
    GLD16(AgC[0] + kn, dA);
    GLD16(AgC[2] + kn, dA + 8192);
    GLD16(AgC[1] + kn, dA + 4096);
    GLD16(AgC[3] + kn, dA + 12288);
    __builtin_amdgcn_s_setprio(1);
#pragma unroll
    for (int i = 0; i < 4; ++i)
#pragma unroll
      for (int j = 0; j < 4; ++j)
        acc[4 + i][j] = __builtin_amdgcn_mfma_f32_16x16x32_bf16(a0[i], b0[j], acc[4 + i][j], 0, 0, 0);
#pragma unroll
    for (int i = 0; i < 4; ++i)
#pragma unroll
      for (int j = 0; j < 4; ++j)
        acc[4 + i][j] = __builtin_amdgcn_mfma_f32_16x16x32_bf16(a1[i], b1[j], acc[4 + i][j], 0, 0, 0);
    __builtin_amdgcn_s_setprio(0);
  }

  // drain junk prefetch of "tile 8" before reusing LDS / ending
  asm volatile("s_waitcnt vmcnt(0)" ::: "memory");
  __syncthreads();

  if (STORE_F32) {
    // fp32: quad-row gives 16 lanes x 4B = 64B contiguous -> direct stores.
    float* C = (float*)Cp;
#pragma unroll
    for (int i8 = 0; i8 < 8; ++i8) {
#pragma unroll
      for (int j = 0; j < 4; ++j) {
        const int row = m0 + wm + i8 * 16 + quad * 4;
        const int col = n0 + wn + j * 16 + r16;
        const float bv = bias ? bias[col] : 0.0f;
#pragma unroll
        for (int rg = 0; rg < 4; ++rg)
          C[(size_t)(row + rg) * Nd + col] = acc[i8][j][rg] + bv;
      }
    }
  } else {
    // bf16: LDS transpose (pitch 264 elems = 528B, 16B-aligned, rows-of-4
    // land 16 banks apart -> ~2-way) then 16B/lane 512B-contiguous stores.
    bf16_t* Es = smem;                           // 128 x 264 = 33792 elems
    bf16_t* C  = (bf16_t*)Cp;
#pragma unroll
    for (int pr = 0; pr < 2; ++pr) {             // m-half rounds
      if (pr) __syncthreads();
      if (wr == pr) {
#pragma unroll
        for (int i8 = 0; i8 < 8; ++i8)
#pragma unroll
          for (int j = 0; j < 4; ++j)
#pragma unroll
            for (int rg = 0; rg < 4; ++rg)
              Es[(size_t)(i8 * 16 + quad * 4 + rg) * 264 + wn + j * 16 + r16] =
                  f2bf(acc[i8][j][rg]);
      }
      __syncthreads();
#pragma unroll
      for (int ps = 0; ps < 8; ++ps) {
        const int row = ps * 16 + (tid >> 5);
        const int cs  = (tid & 31) * 8;
        *(bf16x8*)&C[(size_t)(m0 + pr * 128 + row) * Nd + n0 + cs] =
            *(const bf16x8*)&Es[(size_t)row * 264 + cs];
      }
    }
  }
}

// ---------------------------------------------------------------------------
// Criss-cross attention: one WG per (b, h, r) group; 64x64 scores.
// QKV interleaved [32768][1536] (Q|K|V sections of 512 cols each).
// S = Q K^T * 0.125 (MFMA) -> in-register softmax (x2 folded) -> O = P @ V
// with V staged TRANSPOSED (VsT[dd][k], pitch 70) so PV b-frags are b128 reads.
// Output via LDS for coalesced 128B stores.
// ---------------------------------------------------------------------------
__global__ __launch_bounds__(256) void cc_attn(
    const bf16_t* __restrict__ QKV, bf16_t* __restrict__ Aout)
{
  __shared__ __align__(16) bf16_t Qs[64 * 72];   // Q rows; later P
  __shared__ __align__(16) bf16_t Ks[64 * 72];   // K rows; later O epilogue
  __shared__ __align__(16) bf16_t VsT[64 * 70];  // V^T [dd][k]

  const int gidx = blockIdx.x;                   // 8*8*64 = 4096 groups
  const int r = gidx & 63, h = (gidx >> 6) & 7, b = gidx >> 9;
  const int tid = threadIdx.x, lane = tid & 63, w = tid >> 6;
  const int quad = lane >> 4, r16 = lane & 15;
  const size_t row0 = (size_t)b * 4096 + (size_t)r * 64;   // first token row of group

  // ---- stage: thread t -> (row=t>>2, 16-elem seg=t&3)
  {
    const int row = tid >> 2, seg = tid & 3;
    const bf16_t* gp = QKV + (row0 + row) * 1536 + h * 64 + seg * 16;
    *(bf16x8*)&Qs[row * 72 + seg * 16]     = *(const bf16x8*)&gp[0];
    *(bf16x8*)&Qs[row * 72 + seg * 16 + 8] = *(const bf16x8*)&gp[8];
    *(bf16x8*)&Ks[row * 72 + seg * 16]     = *(const bf16x8*)&gp[512];
    *(bf16x8*)&Ks[row * 72 + seg * 16 + 8] = *(const bf16x8*)&gp[520];
    bf16x8 v0 = *(const bf16x8*)&gp[1024];
    bf16x8 v1 = *(const bf16x8*)&gp[1032];
#pragma unroll
    for (int e = 0; e < 8; ++e) {
      VsT[(seg * 16 + e) * 70 + row]     = v0[e];   // VsT[dd][k=row]
      VsT[(seg * 16 + 8 + e) * 70 + row] = v1[e];
    }
  }
  __syncthreads();

  // ---- S = (Q K^T); wave w owns score rows [16w, 16w+16)
  f32x4 sacc[4] = {};
#pragma unroll
  for (int ks = 0; ks < 2; ++ks) {
    bf16x8 aq = *(const bf16x8*)&Qs[(w * 16 + r16) * 72 + ks * 32 + quad * 8];
#pragma unroll
    for (int nj = 0; nj < 4; ++nj) {
      bf16x8 bk = *(const bf16x8*)&Ks[(nj * 16 + r16) * 72 + ks * 32 + quad * 8];
      sacc[nj] = __builtin_amdgcn_mfma_f32_16x16x32_bf16(aq, bk, sacc[nj], 0, 0, 0);
    }
  }

  // ---- in-register softmax. Lane holds S[row=w*16+quad*4+rg][col=nj*16+r16]*0.125.
  float ex[4][4];                      // [nj][rg]
  float sm[4];
#pragma unroll
  for (int rg = 0; rg < 4; ++rg) {
    float m = -3.0e38f;
#pragma unroll
    for (int nj = 0; nj < 4; ++nj) {
      ex[nj][rg] = sacc[nj][rg] * 0.125f;
      m = fmaxf(m, ex[nj][rg]);
    }
    m = fmaxf(m, __shfl_xor(m, 1));
    m = fmaxf(m, __shfl_xor(m, 2));
    m = fmaxf(m, __shfl_xor(m, 4));
    m = fmaxf(m, __shfl_xor(m, 8));
    float s = 0.f;
#pragma unroll
    for (int nj = 0; nj < 4; ++nj) { ex[nj][rg] = __expf(ex[nj][rg] - m); s += ex[nj][rg]; }
    s += __shfl_xor(s, 1);
    s += __shfl_xor(s, 2);
    s += __shfl_xor(s, 4);
    s += __shfl_xor(s, 8);
    sm[rg] = 2.0f / s;                 // x2: row+col branches identical
  }

  __syncthreads();                     // all waves done reading Qs
#pragma unroll
  for (int nj = 0; nj < 4; ++nj)
#pragma unroll
    for (int rg = 0; rg < 4; ++rg)
      Qs[(w * 16 + quad * 4 + rg) * 72 + nj * 16 + r16] = f2bf(ex[nj][rg] * sm[rg]);
  __syncthreads();

  // ---- O = P @ V via VsT (b128 b-frags)
  f32x4 oacc[4] = {};
#pragma unroll
  for (int ks = 0; ks < 2; ++ks) {
    bf16x8 ap = *(const bf16x8*)&Qs[(w * 16 + r16) * 72 + ks * 32 + quad * 8];
#pragma unroll
    for (int nj = 0; nj < 4; ++nj) {
      bf16x8 bv = *(const bf16x8*)&VsT[(nj * 16 + r16) * 70 + ks * 32 + quad * 8];
      oacc[nj] = __builtin_amdgcn_mfma_f32_16x16x32_bf16(ap, bv, oacc[nj], 0, 0, 0);
    }
  }

  // ---- epilogue through LDS (reuse Ks, pitch 72) -> 128B-contiguous stores
  {
    bf16_t* Es = Ks;
#pragma unroll
    for (int nj = 0; nj < 4; ++nj)
#pragma unroll
      for (int rg = 0; rg < 4; ++rg)
        Es[(w * 16 + quad * 4 + rg) * 72 + nj * 16 + r16] = f2bf(oacc[nj][rg]);
    __syncthreads();
    const size_t obase = row0 * 512 + (size_t)h * 64;   // Aout [32768][512]
#pragma unroll
    for (int rd = 0; rd < 2; ++rd) {
      const int row = rd * 32 + (tid >> 3);
      const int col = (tid & 7) * 8;
      *(bf16x8*)&Aout[obase + (size_t)row * 512 + col] = *(const bf16x8*)&Es[row * 72 + col];
    }
  }
}

// ---------------------------------------------------------------------------
extern "C" void kernel_launch(void* const* d_in, const int* in_sizes, int n_in,
                              void* d_out, int out_size, void* d_ws, size_t ws_size,
                              hipStream_t stream)
{
  const float* x  = (const float*)d_in[0];
  const float* Wq = (const float*)d_in[1];
  const float* Wk = (const float*)d_in[2];
  const float* Wv = (const float*)d_in[3];
  const float* Wo = (const float*)d_in[4];
  const float* bo = (const float*)d_in[5];

  bf16_t* ws = (bf16_t*)d_ws;
  // workspace (bf16 elems):
  //   WT  : 4 x 262144   @ 0           (Wq|Wk|Wv rows 0..1535 stacked, then Wo)
  //   xbf : 16,777,216   @ 1,048,576   (dead after QKV GEMM; Ab aliases it)
  //   QKV : 50,331,648   @ 17,825,792  ([32768][1536] interleaved Q|K|V)
  // total 68,157,440 elems = 136,314,880 bytes
  // NOTE: gemm256's final-iteration junk prefetch reads up to ~1KB past each
  // operand's end; all operands are interior to d_ws, so reads stay in-bounds.
  bf16_t* WT  = ws;
  bf16_t* xbf = ws + 1048576;
  bf16_t* QKV = xbf + 16777216;
  bf16_t* Ab  = xbf;

  cvt_x<<<dim3(16384), 256, 0, stream>>>(x, xbf, 4194304);
  wt_kernel<<<dim3(16, 16, 4), dim3(32, 8), 0, stream>>>(Wq, Wk, Wv, Wo, WT);

  // fused QKV projection: B = stacked WTq|WTk|WTv (1536 rows), 256x256 tiles
  gemm256<false><<<dim3(6, 128), 512, 0, stream>>>(xbf, WT, QKV, nullptr, 1536);

  cc_attn<<<dim3(4096), 256, 0, stream>>>(QKV, Ab);

  gemm256<true><<<dim3(2, 128), 512, 0, stream>>>(Ab, WT + 786432, d_out, bo, 512);
}

// Round 4
// 232.414 us; speedup vs baseline: 1.0071x; 1.0071x over previous
//
#include <hip/hip_runtime.h>
#include <hip/hip_bf16.h>
#include <stdint.h>

// CrissCrossAttention, MI355X gfx950.
// out = 2 * row-attention (column branch collapses exactly onto row branch).
// Pipeline: cvt x->bf16 | transpose W->bf16 | fused QKV GEMM | per-(b,h,r) MFMA
//           attention | GEMM(+bias) -> fp32 out.
// r10 == r9 resubmit (round 3 failed at container level, not kernel level:
//     no pass/fail verdict was produced; r9 audit found no OOB / divergent
//     barrier / fault class issue).
// r9: gemm256 K-loop software-pipelined at fragment level: 8 phases x 8 MFMA,
//     each phase issues the NEXT phase's ds_reads (a[2] chunk ping-pong,
//     bk[2] K-half sets) so every read has a full MFMA cluster of latency
//     cover. r7/r8 tied at 60us/33% because frag reads were consumed at
//     issue+0 in lockstep bursts. One barrier + one aged vmcnt(0) per K-tile;
//     GLDs issued at ph0, waited 6.5 phases later. t=7 skips prefetch.

typedef __bf16 bf16_t;
typedef __bf16 bf16x4v __attribute__((ext_vector_type(4)));
typedef __bf16 bf16x8 __attribute__((ext_vector_type(8)));
typedef float  f32x4  __attribute__((ext_vector_type(4)));

#define GLD16(gp, lp)                                                                  \
  __builtin_amdgcn_global_load_lds((__attribute__((address_space(1))) const void*)(gp),\
                                   (__attribute__((address_space(3))) void*)(lp),      \
                                   16, 0, 0)

__device__ __forceinline__ float  bf2f(bf16_t x) { return (float)x; }
__device__ __forceinline__ bf16_t f2bf(float x)  { return (bf16_t)x; }

// ---------------------------------------------------------------------------
// fp32 -> bf16 conversion, float4 loads.
// ---------------------------------------------------------------------------
__global__ __launch_bounds__(256) void cvt_x(const float* __restrict__ X,
                                             bf16_t* __restrict__ Y, int n4)
{
  int i = blockIdx.x * blockDim.x + threadIdx.x;
  if (i < n4) {
    float4 v = ((const float4*)X)[i];
    bf16x4v o;
    o[0] = f2bf(v.x); o[1] = f2bf(v.y); o[2] = f2bf(v.z); o[3] = f2bf(v.w);
    ((bf16x4v*)Y)[i] = o;
  }
}

// ---------------------------------------------------------------------------
// Weight transpose + cast: WT[n][k] = (bf16)W[k][n], 512x512, z selects matrix.
// ---------------------------------------------------------------------------
__global__ void wt_kernel(const float* __restrict__ Wq, const float* __restrict__ Wk,
                          const float* __restrict__ Wv, const float* __restrict__ Wo,
                          bf16_t* __restrict__ WT)
{
  __shared__ bf16_t tile[32][33];
  const int mat = blockIdx.z;
  const float* W = (mat == 0) ? Wq : (mat == 1) ? Wk : (mat == 2) ? Wv : Wo;
  bf16_t* dst = WT + (size_t)mat * 262144;
  const int tx = threadIdx.x, ty = threadIdx.y;          // 32 x 8
  const int x0 = blockIdx.x * 32, y0 = blockIdx.y * 32;
#pragma unroll
  for (int i = 0; i < 32; i += 8)
    tile[ty + i][tx] = f2bf(W[(size_t)(y0 + ty + i) * 512 + x0 + tx]);
  __syncthreads();
#pragma unroll
  for (int i = 0; i < 32; i += 8)
    dst[(size_t)(x0 + ty + i) * 512 + y0 + tx] = tile[tx][ty + i];
}

// ---------------------------------------------------------------------------
// GEMM: C[M,Nd] = A[M,512] @ BT[Nd,512]^T (+bias), bf16 in, fp32 acc.
// 256x256 tile, 512 threads = 8 waves (2M x 4N), BK=64, K=512 -> 8 K-tiles.
// LDS 128KB: double-buffered A[256][64] + B[256][64], XOR-swizzled rows
//   (logical (row,seg16B) lives at byte row*128 + (seg*16 ^ ((row&7)<<4));
//    global_load_lds dest stays linear, source address pre-permuted - rule 21).
// K-tile = 8 phases x 8 MFMA (A-chunk c=0..3 x kk=0..1); phase p issues the
// ds_reads for phase p+1 (a[2] ping-pong; bk[2] per-kk sets read at pre/ph3).
// Tile boundary (between ph6 and ph7): vmcnt(0) [8 GLDs issued at ph0, ~6
// phases old -> free] + barrier + read next tile's bk0/a-c0k0 under ph7's
// MFMA. k0 frag set is dead by ph3 -> boundary overwrite is safe.
// XCD swizzle (proven r5): each XCD owns a contiguous m-band, n fastest.
// ---------------------------------------------------------------------------
template <bool STORE_F32>
__global__ __launch_bounds__(512, 2) void gemm256(
    const bf16_t* __restrict__ A,
    const bf16_t* __restrict__ BT,
    void* __restrict__ Cp,
    const float* __restrict__ bias,
    int Nd)
{
  __shared__ __align__(16) bf16_t smem[65536];   // 128 KB
  bf16_t* const sA = smem;            // [2][16384] = dbuf x 256 rows x 64
  bf16_t* const sB = smem + 32768;    // [2][16384]

  const int tid  = threadIdx.x;
  const int lane = tid & 63, w = tid >> 6;
  const int quad = lane >> 4, r16 = lane & 15;
  const int wr = w >> 2, wc = w & 3;             // wave grid 2 x 4
  const int wm = wr * 128, wn = wc * 64;

  // XCD-aware remap (8 XCDs, round-robin dispatch). gridDim.y = 128 m-tiles.
  const int G = gridDim.x;
  const int l = blockIdx.y * G + blockIdx.x;
  const int xcd = l & 7, slot = l >> 3;
  const int mb = xcd * (gridDim.y >> 3) + slot / G;
  const int nb = slot % G;
  const int m0 = mb * 256, n0 = nb * 256;

  // staging: call c stages rows [c*64, c*64+64); thread t -> row=t>>3,
  // 16B seg = (t&7) ^ (row&7)  (inverse of the read-side XOR swizzle).
  const int srow = tid >> 3;
  const int sseg = (tid & 7) ^ (srow & 7);
  const bf16_t* Ag = A  + (size_t)(m0 + srow) * 512 + sseg * 8;
  const bf16_t* Bg = BT + (size_t)(n0 + srow) * 512 + sseg * 8;
  const int sdst = w * 512;                      // per-wave 1KB chunk (elems)

  // prologue: tile 0 -> buf 0.
  GLD16(Bg,           sB + sdst);
  GLD16(Bg + 32768,   sB + 4096  + sdst);
  GLD16(Bg + 65536,   sB + 8192  + sdst);
  GLD16(Bg + 98304,   sB + 12288 + sdst);
  GLD16(Ag,           sA + sdst);
  GLD16(Ag + 32768,   sA + 4096  + sdst);
  GLD16(Ag + 65536,   sA + 8192  + sdst);
  GLD16(Ag + 98304,   sA + 12288 + sdst);

  f32x4 acc[8][4] = {};

  const int xsw   = (r16 & 7) << 4;              // read-side XOR swizzle
  const int koff0 = (quad * 16) ^ xsw;           // kk=0 within-row byte
  const int koff1 = (64 + quad * 16) ^ xsw;      // kk=1

  bf16x8 bk[2][4];                               // B frag sets per kk
  bf16x8 a[2][2];                                // A chunk ping-pong (2 i-frags)

#define RD_B(dst, base, kof)                                                     \
  _Pragma("unroll") for (int j_ = 0; j_ < 4; ++j_)                               \
    dst[j_] = *(const bf16x8*)((base) + (size_t)(wn + j_ * 16 + r16) * 128 + (kof));
#define RD_A2(dst, base, rowoff, kof)                                            \
  _Pragma("unroll") for (int i_ = 0; i_ < 2; ++i_)                               \
    dst[i_] = *(const bf16x8*)((base) + (size_t)(wm + (rowoff) + i_ * 16 + r16) * 128 + (kof));
#define MFMA8(r0, r1, av, bv)                                                    \
  __builtin_amdgcn_s_setprio(1);                                                 \
  _Pragma("unroll") for (int j_ = 0; j_ < 4; ++j_) {                             \
    acc[r0][j_] = __builtin_amdgcn_mfma_f32_16x16x32_bf16(av[0], bv[j_], acc[r0][j_], 0, 0, 0); \
    acc[r1][j_] = __builtin_amdgcn_mfma_f32_16x16x32_bf16(av[1], bv[j_], acc[r1][j_], 0, 0, 0); \
  }                                                                              \
  __builtin_amdgcn_s_setprio(0);

  asm volatile("s_waitcnt vmcnt(0)" ::: "memory");
  __builtin_amdgcn_s_barrier();

  // pre-read tile0 ph0 operands: B k0-set + A chunk0 k0 (buf 0)
  RD_B(bk[0], (const char*)sB, koff0);
  RD_A2(a[0], (const char*)sA, 0, koff0);

#pragma unroll
  for (int t = 0; t < 8; ++t) {
    const int p = t & 1, pn = p ^ 1;
    const char* sAp  = (const char*)(sA + p  * 16384);
    const char* sBp  = (const char*)(sB + p  * 16384);
    const char* sApn = (const char*)(sA + pn * 16384);
    const char* sBpn = (const char*)(sB + pn * 16384);

    // ph0: issue all 8 GLDs for tile t+1 (waited ~6.5 phases later)
    if (t < 7) {
      const int kn = (t + 1) * 64;
      bf16_t* const dA = sA + pn * 16384 + sdst;
      bf16_t* const dB = sB + pn * 16384 + sdst;
      GLD16(Bg + kn,          dB);
      GLD16(Bg + kn + 32768,  dB + 4096);
      GLD16(Bg + kn + 65536,  dB + 8192);
      GLD16(Bg + kn + 98304,  dB + 12288);
      GLD16(Ag + kn,          dA);
      GLD16(Ag + kn + 32768,  dA + 4096);
      GLD16(Ag + kn + 65536,  dA + 8192);
      GLD16(Ag + kn + 98304,  dA + 12288);
    }
    RD_A2(a[1], sAp, 32, koff0);                 // c1 k0
    MFMA8(0, 1, a[0], bk[0]);                    // ph0: c0 k0

    RD_A2(a[0], sAp, 64, koff0);                 // c2 k0
    MFMA8(2, 3, a[1], bk[0]);                    // ph1: c1 k0

    RD_A2(a[1], sAp, 96, koff0);                 // c3 k0
    MFMA8(4, 5, a[0], bk[0]);                    // ph2: c2 k0

    RD_B(bk[1], sBp, koff1);                     // B k1-set
    RD_A2(a[0], sAp, 0, koff1);                  // c0 k1
    MFMA8(6, 7, a[1], bk[0]);                    // ph3: c3 k0  (k0 set dies here)

    RD_A2(a[1], sAp, 32, koff1);                 // c1 k1
    MFMA8(0, 1, a[0], bk[1]);                    // ph4: c0 k1

    RD_A2(a[0], sAp, 64, koff1);                 // c2 k1
    MFMA8(2, 3, a[1], bk[1]);                    // ph5: c1 k1

    RD_A2(a[1], sAp, 96, koff1);                 // c3 k1
    MFMA8(4, 5, a[0], bk[1]);                    // ph6: c2 k1

    // tile boundary: fills for t+1 are ~6 phases old -> vmcnt(0) is free.
    // Boundary reads (next tile's bk0 + a-c0k0) ride under ph7's MFMA.
    if (t < 7) {
      asm volatile("s_waitcnt vmcnt(0)" ::: "memory");
      __builtin_amdgcn_s_barrier();
      RD_B(bk[0], sBpn, koff0);
      RD_A2(a[0], sApn, 0, koff0);
    }
    MFMA8(6, 7, a[1], bk[1]);                    // ph7: c3 k1
  }

  __syncthreads();                               // LDS reuse safety (epilogue)

  if (STORE_F32) {
    // fp32: quad-row gives 16 lanes x 4B = 64B contiguous -> direct stores.
    float* C = (float*)Cp;
#pragma unroll
    for (int i8 = 0; i8 < 8; ++i8) {
#pragma unroll
      for (int j = 0; j < 4; ++j) {
        const int row = m0 + wm + i8 * 16 + quad * 4;
        const int col = n0 + wn + j * 16 + r16;
        const float bv = bias ? bias[col] : 0.0f;
#pragma unroll
        for (int rg = 0; rg < 4; ++rg)
          C[(size_t)(row + rg) * Nd + col] = acc[i8][j][rg] + bv;
      }
    }
  } else {
    // bf16: LDS transpose (pitch 264 elems = 528B, 16B-aligned, rows-of-4
    // land 16 banks apart -> ~2-way) then 16B/lane 512B-contiguous stores.
    bf16_t* Es = smem;                           // 128 x 264 = 33792 elems
    bf16_t* C  = (bf16_t*)Cp;
#pragma unroll
    for (int pr = 0; pr < 2; ++pr) {             // m-half rounds
      if (pr) __syncthreads();
      if (wr == pr) {
#pragma unroll
        for (int i8 = 0; i8 < 8; ++i8)
#pragma unroll
          for (int j = 0; j < 4; ++j)
#pragma unroll
            for (int rg = 0; rg < 4; ++rg)
              Es[(size_t)(i8 * 16 + quad * 4 + rg) * 264 + wn + j * 16 + r16] =
                  f2bf(acc[i8][j][rg]);
      }
      __syncthreads();
#pragma unroll
      for (int ps = 0; ps < 8; ++ps) {
        const int row = ps * 16 + (tid >> 5);
        const int cs  = (tid & 31) * 8;
        *(bf16x8*)&C[(size_t)(m0 + pr * 128 + row) * Nd + n0 + cs] =
            *(const bf16x8*)&Es[(size_t)row * 264 + cs];
      }
    }
  }
#undef RD_B
#undef RD_A2
#undef MFMA8
}

// ---------------------------------------------------------------------------
// Criss-cross attention: one WG per (b, h, r) group; 64x64 scores.
// QKV interleaved [32768][1536] (Q|K|V sections of 512 cols each).
// S = Q K^T * 0.125 (MFMA) -> in-register softmax (x2 folded) -> O = P @ V
// with V staged TRANSPOSED (VsT[dd][k], pitch 70) so PV b-frags are b128 reads.
// Output via LDS for coalesced 128B stores.
// ---------------------------------------------------------------------------
__global__ __launch_bounds__(256) void cc_attn(
    const bf16_t* __restrict__ QKV, bf16_t* __restrict__ Aout)
{
  __shared__ __align__(16) bf16_t Qs[64 * 72];   // Q rows; later P
  __shared__ __align__(16) bf16_t Ks[64 * 72];   // K rows; later O epilogue
  __shared__ __align__(16) bf16_t VsT[64 * 70];  // V^T [dd][k]

  const int gidx = blockIdx.x;                   // 8*8*64 = 4096 groups
  const int r = gidx & 63, h = (gidx >> 6) & 7, b = gidx >> 9;
  const int tid = threadIdx.x, lane = tid & 63, w = tid >> 6;
  const int quad = lane >> 4, r16 = lane & 15;
  const size_t row0 = (size_t)b * 4096 + (size_t)r * 64;   // first token row of group

  // ---- stage: thread t -> (row=t>>2, 16-elem seg=t&3)
  {
    const int row = tid >> 2, seg = tid & 3;
    const bf16_t* gp = QKV + (row0 + row) * 1536 + h * 64 + seg * 16;
    *(bf16x8*)&Qs[row * 72 + seg * 16]     = *(const bf16x8*)&gp[0];
    *(bf16x8*)&Qs[row * 72 + seg * 16 + 8] = *(const bf16x8*)&gp[8];
    *(bf16x8*)&Ks[row * 72 + seg * 16]     = *(const bf16x8*)&gp[512];
    *(bf16x8*)&Ks[row * 72 + seg * 16 + 8] = *(const bf16x8*)&gp[520];
    bf16x8 v0 = *(const bf16x8*)&gp[1024];
    bf16x8 v1 = *(const bf16x8*)&gp[1032];
#pragma unroll
    for (int e = 0; e < 8; ++e) {
      VsT[(seg * 16 + e) * 70 + row]     = v0[e];   // VsT[dd][k=row]
      VsT[(seg * 16 + 8 + e) * 70 + row] = v1[e];
    }
  }
  __syncthreads();

  // ---- S = (Q K^T); wave w owns score rows [16w, 16w+16)
  f32x4 sacc[4] = {};
#pragma unroll
  for (int ks = 0; ks < 2; ++ks) {
    bf16x8 aq = *(const bf16x8*)&Qs[(w * 16 + r16) * 72 + ks * 32 + quad * 8];
#pragma unroll
    for (int nj = 0; nj < 4; ++nj) {
      bf16x8 bk = *(const bf16x8*)&Ks[(nj * 16 + r16) * 72 + ks * 32 + quad * 8];
      sacc[nj] = __builtin_amdgcn_mfma_f32_16x16x32_bf16(aq, bk, sacc[nj], 0, 0, 0);
    }
  }

  // ---- in-register softmax. Lane holds S[row=w*16+quad*4+rg][col=nj*16+r16]*0.125.
  float ex[4][4];                      // [nj][rg]
  float sm[4];
#pragma unroll
  for (int rg = 0; rg < 4; ++rg) {
    float m = -3.0e38f;
#pragma unroll
    for (int nj = 0; nj < 4; ++nj) {
      ex[nj][rg] = sacc[nj][rg] * 0.125f;
      m = fmaxf(m, ex[nj][rg]);
    }
    m = fmaxf(m, __shfl_xor(m, 1));
    m = fmaxf(m, __shfl_xor(m, 2));
    m = fmaxf(m, __shfl_xor(m, 4));
    m = fmaxf(m, __shfl_xor(m, 8));
    float s = 0.f;
#pragma unroll
    for (int nj = 0; nj < 4; ++nj) { ex[nj][rg] = __expf(ex[nj][rg] - m); s += ex[nj][rg]; }
    s += __shfl_xor(s, 1);
    s += __shfl_xor(s, 2);
    s += __shfl_xor(s, 4);
    s += __shfl_xor(s, 8);
    sm[rg] = 2.0f / s;                 // x2: row+col branches identical
  }

  __syncthreads();                     // all waves done reading Qs
#pragma unroll
  for (int nj = 0; nj < 4; ++nj)
#pragma unroll
    for (int rg = 0; rg < 4; ++rg)
      Qs[(w * 16 + quad * 4 + rg) * 72 + nj * 16 + r16] = f2bf(ex[nj][rg] * sm[rg]);
  __syncthreads();

  // ---- O = P @ V via VsT (b128 b-frags)
  f32x4 oacc[4] = {};
#pragma unroll
  for (int ks = 0; ks < 2; ++ks) {
    bf16x8 ap = *(const bf16x8*)&Qs[(w * 16 + r16) * 72 + ks * 32 + quad * 8];
#pragma unroll
    for (int nj = 0; nj < 4; ++nj) {
      bf16x8 bv = *(const bf16x8*)&VsT[(nj * 16 + r16) * 70 + ks * 32 + quad * 8];
      oacc[nj] = __builtin_amdgcn_mfma_f32_16x16x32_bf16(ap, bv, oacc[nj], 0, 0, 0);
    }
  }

  // ---- epilogue through LDS (reuse Ks, pitch 72) -> 128B-contiguous stores
  {
    bf16_t* Es = Ks;
#pragma unroll
    for (int nj = 0; nj < 4; ++nj)
#pragma unroll
      for (int rg = 0; rg < 4; ++rg)
        Es[(w * 16 + quad * 4 + rg) * 72 + nj * 16 + r16] = f2bf(oacc[nj][rg]);
    __syncthreads();
    const size_t obase = row0 * 512 + (size_t)h * 64;   // Aout [32768][512]
#pragma unroll
    for (int rd = 0; rd < 2; ++rd) {
      const int row = rd * 32 + (tid >> 3);
      const int col = (tid & 7) * 8;
      *(bf16x8*)&Aout[obase + (size_t)row * 512 + col] = *(const bf16x8*)&Es[row * 72 + col];
    }
  }
}

// ---------------------------------------------------------------------------
extern "C" void kernel_launch(void* const* d_in, const int* in_sizes, int n_in,
                              void* d_out, int out_size, void* d_ws, size_t ws_size,
                              hipStream_t stream)
{
  const float* x  = (const float*)d_in[0];
  const float* Wq = (const float*)d_in[1];
  const float* Wk = (const float*)d_in[2];
  const float* Wv = (const float*)d_in[3];
  const float* Wo = (const float*)d_in[4];
  const float* bo = (const float*)d_in[5];

  bf16_t* ws = (bf16_t*)d_ws;
  // workspace (bf16 elems):
  //   WT  : 4 x 262144   @ 0           (Wq|Wk|Wv rows 0..1535 stacked, then Wo)
  //   xbf : 16,777,216   @ 1,048,576   (dead after QKV GEMM; Ab aliases it)
  //   QKV : 50,331,648   @ 17,825,792  ([32768][1536] interleaved Q|K|V)
  // total 68,157,440 elems = 136,314,880 bytes
  bf16_t* WT  = ws;
  bf16_t* xbf = ws + 1048576;
  bf16_t* QKV = xbf + 16777216;
  bf16_t* Ab  = xbf;

  cvt_x<<<dim3(16384), 256, 0, stream>>>(x, xbf, 4194304);
  wt_kernel<<<dim3(16, 16, 4), dim3(32, 8), 0, stream>>>(Wq, Wk, Wv, Wo, WT);

  // fused QKV projection: B = stacked WTq|WTk|WTv (1536 rows), 256x256 tiles
  gemm256<false><<<dim3(6, 128), 512, 0, stream>>>(xbf, WT, QKV, nullptr, 1536);

  cc_attn<<<dim3(4096), 256, 0, stream>>>(QKV, Ab);

  gemm256<true><<<dim3(2, 128), 512, 0, stream>>>(Ab, WT + 786432, d_out, bo, 512);
}

// Round 5
// 229.941 us; speedup vs baseline: 1.0179x; 1.0108x over previous
//
#include <hip/hip_runtime.h>
#include <hip/hip_bf16.h>
#include <stdint.h>

// CrissCrossAttention, MI355X gfx950.
// out = 2 * row-attention (column branch collapses exactly onto row branch).
// Pipeline: prep (cvt x->bf16 + transpose W->bf16) | fused QKV GEMM |
//           per-(b,h,r) MFMA attention | GEMM(+bias) -> fp32 out.
// r11: GEMM moved 256x256/512thr/128KB (1 block/CU) -> 128x128/256thr/64KB
//      (2 blocks/CU). r7-r9 tied at ~60us/34% because fill (first-tile
//      latency) and drain (C-store burst) had no co-resident block to hide
//      under; intra-block scheduling couldn't touch that. Keeps r9's
//      fragment-pipelined K-loop + XOR swizzle + XCD remap. cvt_x and
//      wt_kernel merged into one launch (prep).

typedef __bf16 bf16_t;
typedef __bf16 bf16x4v __attribute__((ext_vector_type(4)));
typedef __bf16 bf16x8 __attribute__((ext_vector_type(8)));
typedef float  f32x4  __attribute__((ext_vector_type(4)));

#define GLD16(gp, lp)                                                                  \
  __builtin_amdgcn_global_load_lds((__attribute__((address_space(1))) const void*)(gp),\
                                   (__attribute__((address_space(3))) void*)(lp),      \
                                   16, 0, 0)

__device__ __forceinline__ float  bf2f(bf16_t x) { return (float)x; }
__device__ __forceinline__ bf16_t f2bf(float x)  { return (bf16_t)x; }

// ---------------------------------------------------------------------------
// prep: fused (a) fp32->bf16 conversion of x (float4 loads) and
//              (b) weight transpose+cast WT[n][k] = (bf16)W[k][n].
// blocks [0, 16384): cvt; blocks [16384, 17408): wt (64 per matrix... 256).
// ---------------------------------------------------------------------------
__global__ __launch_bounds__(256) void prep(
    const float* __restrict__ x,
    const float* __restrict__ Wq, const float* __restrict__ Wk,
    const float* __restrict__ Wv, const float* __restrict__ Wo,
    bf16_t* __restrict__ xbf, bf16_t* __restrict__ WT)
{
  __shared__ bf16_t tile[32][33];
  const int bid = blockIdx.x, tid = threadIdx.x;
  if (bid < 16384) {
    const int i = bid * 256 + tid;                 // 16384*256 = 4194304 exact
    float4 v = ((const float4*)x)[i];
    bf16x4v o;
    o[0] = f2bf(v.x); o[1] = f2bf(v.y); o[2] = f2bf(v.z); o[3] = f2bf(v.w);
    ((bf16x4v*)xbf)[i] = o;
  } else {
    const int k = bid - 16384;                     // 0..1023
    const int mat = k >> 8;                        // 0..3
    const float* W = (mat == 0) ? Wq : (mat == 1) ? Wk : (mat == 2) ? Wv : Wo;
    bf16_t* dst = WT + (size_t)mat * 262144;
    const int bx = k & 15, by = (k >> 4) & 15;
    const int tx = tid & 31, ty = tid >> 5;        // 32 x 8
    const int x0 = bx * 32, y0 = by * 32;
#pragma unroll
    for (int i = 0; i < 32; i += 8)
      tile[ty + i][tx] = f2bf(W[(size_t)(y0 + ty + i) * 512 + x0 + tx]);
    __syncthreads();
#pragma unroll
    for (int i = 0; i < 32; i += 8)
      dst[(size_t)(x0 + ty + i) * 512 + y0 + tx] = tile[tx][ty + i];
  }
}

// ---------------------------------------------------------------------------
// GEMM: C[M,Nd] = A[M,512] @ BT[Nd,512]^T (+bias), bf16 in, fp32 acc.
// 128x128 tile, 256 threads = 4 waves (2M x 2N, 64x64 each), BK=64,
// K=512 -> 8 K-tiles. LDS 64 KB: dbuf A[128][64] + B[128][64], XOR-swizzled
// rows (logical (row,seg16B) at byte row*128 + (seg*16 ^ ((row&7)<<4));
// global_load_lds dest linear, source pre-permuted - rule 21).
// 2 blocks/CU co-resident (64KB LDS, <=256 VGPR via launch_bounds(256,2)):
// one block's prologue-fill and epilogue-drain hide under the other's K-loop
// -- the overhead r7-r9's 1-block/CU structure could not hide.
// K-loop: r9-style fragment pipeline: pre-read k0 frag sets; per tile:
// issue 8 GLDs (t+1) | read k1 sets | 16 MFMA (k0) | vmcnt(0)+barrier +
// read next k0 sets | 16 MFMA (k1).
// XCD swizzle (proven r5): each XCD owns a contiguous m-band, n fastest.
// ---------------------------------------------------------------------------
template <bool STORE_F32>
__global__ __launch_bounds__(256, 2) void gemm128(
    const bf16_t* __restrict__ A,
    const bf16_t* __restrict__ BT,
    void* __restrict__ Cp,
    const float* __restrict__ bias,
    int Nd)
{
  __shared__ __align__(16) bf16_t smem[32768];   // 64 KB
  bf16_t* const sA = smem;            // [2][8192] = dbuf x 128 rows x 64
  bf16_t* const sB = smem + 16384;    // [2][8192]

  const int tid  = threadIdx.x;
  const int lane = tid & 63, w = tid >> 6;
  const int quad = lane >> 4, r16 = lane & 15;
  const int wr = w >> 1, wc = w & 1;             // wave grid 2 x 2
  const int wm = wr * 64, wn = wc * 64;

  // XCD-aware remap (8 XCDs, round-robin dispatch). gridDim.y = 256 m-tiles.
  const int G = gridDim.x;
  const int l = blockIdx.y * G + blockIdx.x;
  const int xcd = l & 7, slot = l >> 3;
  const int mb = xcd * (gridDim.y >> 3) + slot / G;
  const int nb = slot % G;
  const int m0 = mb * 128, n0 = nb * 128;

  // staging: call c stages rows [c*32, c*32+32); thread t -> row=t>>3,
  // 16B seg = (t&7) ^ (row&7)  (inverse of the read-side XOR swizzle).
  const int srow = tid >> 3;                     // 0..31
  const int sseg = (tid & 7) ^ (srow & 7);
  const bf16_t* Ag = A  + (size_t)(m0 + srow) * 512 + sseg * 8;
  const bf16_t* Bg = BT + (size_t)(n0 + srow) * 512 + sseg * 8;
  const int sdst = tid * 8;                      // per-thread 16B dest (elems)

  // prologue: tile 0 -> buf 0.  (chunk c: +c*32 rows = c*16384 elems global,
  //                              +c*2048 elems LDS)
  GLD16(Bg,          sB + sdst);
  GLD16(Bg + 16384,  sB + 2048 + sdst);
  GLD16(Bg + 32768,  sB + 4096 + sdst);
  GLD16(Bg + 49152,  sB + 6144 + sdst);
  GLD16(Ag,          sA + sdst);
  GLD16(Ag + 16384,  sA + 2048 + sdst);
  GLD16(Ag + 32768,  sA + 4096 + sdst);
  GLD16(Ag + 49152,  sA + 6144 + sdst);

  f32x4 acc[4][4] = {};

  const int xsw   = (r16 & 7) << 4;              // read-side XOR swizzle
  const int koff0 = (quad * 16) ^ xsw;           // kk=0 within-row byte
  const int koff1 = (64 + quad * 16) ^ xsw;      // kk=1

  bf16x8 a0[4], a1[4], b0[4], b1[4];

#define RD4(dst, base, roff, kof)                                                \
  _Pragma("unroll") for (int i_ = 0; i_ < 4; ++i_)                               \
    dst[i_] = *(const bf16x8*)((base) + (size_t)((roff) + i_ * 16 + r16) * 128 + (kof));
#define MFMA16(av, bv)                                                           \
  __builtin_amdgcn_s_setprio(1);                                                 \
  _Pragma("unroll") for (int i_ = 0; i_ < 4; ++i_)                               \
  _Pragma("unroll") for (int j_ = 0; j_ < 4; ++j_)                               \
    acc[i_][j_] = __builtin_amdgcn_mfma_f32_16x16x32_bf16(av[i_], bv[j_], acc[i_][j_], 0, 0, 0); \
  __builtin_amdgcn_s_setprio(0);

  asm volatile("s_waitcnt vmcnt(0)" ::: "memory");
  __builtin_amdgcn_s_barrier();
  asm volatile("" ::: "memory");

  // pre-read tile0 k0 frag sets (buf 0)
  RD4(a0, (const char*)sA, wm, koff0);
  RD4(b0, (const char*)sB, wn, koff0);

#pragma unroll
  for (int t = 0; t < 8; ++t) {
    const int p = t & 1, pn = p ^ 1;
    const char* sAp  = (const char*)(sA + p  * 8192);
    const char* sBp  = (const char*)(sB + p  * 8192);
    const char* sApn = (const char*)(sA + pn * 8192);
    const char* sBpn = (const char*)(sB + pn * 8192);

    // issue all 8 GLDs for tile t+1 into the other buffer
    if (t < 7) {
      const int kn = (t + 1) * 64;
      bf16_t* const dA = sA + pn * 8192 + sdst;
      bf16_t* const dB = sB + pn * 8192 + sdst;
      GLD16(Bg + kn,          dB);
      GLD16(Bg + kn + 16384,  dB + 2048);
      GLD16(Bg + kn + 32768,  dB + 4096);
      GLD16(Bg + kn + 49152,  dB + 6144);
      GLD16(Ag + kn,          dA);
      GLD16(Ag + kn + 16384,  dA + 2048);
      GLD16(Ag + kn + 32768,  dA + 4096);
      GLD16(Ag + kn + 49152,  dA + 6144);
    }
    // k1 frag reads ride under the k0 MFMA cluster
    RD4(a1, sAp, wm, koff1);
    RD4(b1, sBp, wn, koff1);
    MFMA16(a0, b0);                              // k0

    if (t < 7) {
      asm volatile("s_waitcnt vmcnt(0)" ::: "memory");
      __builtin_amdgcn_s_barrier();
      asm volatile("" ::: "memory");
      // next tile's k0 frag reads ride under this tile's k1 MFMA
      RD4(a0, sApn, wm, koff0);
      RD4(b0, sBpn, wn, koff0);
    }
    MFMA16(a1, b1);                              // k1
  }

  __syncthreads();                               // all frag reads done

  if (STORE_F32) {
    // fp32: quad-row gives 16 lanes x 4B = 64B contiguous -> direct stores.
    float* C = (float*)Cp;
#pragma unroll
    for (int i = 0; i < 4; ++i) {
#pragma unroll
      for (int j = 0; j < 4; ++j) {
        const int row = m0 + wm + i * 16 + quad * 4;
        const int col = n0 + wn + j * 16 + r16;
        const float bv = bias ? bias[col] : 0.0f;
#pragma unroll
        for (int rg = 0; rg < 4; ++rg)
          C[(size_t)(row + rg) * Nd + col] = acc[i][j][rg] + bv;
      }
    }
  } else {
    // bf16: LDS transpose (pitch 136 elems = 272B; rows-of-4 land 16 banks
    // apart -> 2-way, free) then 16B/lane 256B-contiguous stores.
    bf16_t* Es = smem;                           // 128 x 136 = 17408 elems
    bf16_t* C  = (bf16_t*)Cp;
#pragma unroll
    for (int i = 0; i < 4; ++i)
#pragma unroll
      for (int j = 0; j < 4; ++j)
#pragma unroll
        for (int rg = 0; rg < 4; ++rg)
          Es[(size_t)(wm + i * 16 + quad * 4 + rg) * 136 + wn + j * 16 + r16] =
              f2bf(acc[i][j][rg]);
    __syncthreads();
#pragma unroll
    for (int ps = 0; ps < 8; ++ps) {
      const int row = ps * 16 + (tid >> 4);
      const int cs  = (tid & 15) * 8;
      *(bf16x8*)&C[(size_t)(m0 + row) * Nd + n0 + cs] =
          *(const bf16x8*)&Es[(size_t)row * 136 + cs];
    }
  }
#undef RD4
#undef MFMA16
}

// ---------------------------------------------------------------------------
// Criss-cross attention: one WG per (b, h, r) group; 64x64 scores.
// QKV interleaved [32768][1536] (Q|K|V sections of 512 cols each).
// S = Q K^T * 0.125 (MFMA) -> in-register softmax (x2 folded) -> O = P @ V
// with V staged TRANSPOSED (VsT[dd][k], pitch 70) so PV b-frags are b128 reads.
// Output via LDS for coalesced 128B stores.
// ---------------------------------------------------------------------------
__global__ __launch_bounds__(256) void cc_attn(
    const bf16_t* __restrict__ QKV, bf16_t* __restrict__ Aout)
{
  __shared__ __align__(16) bf16_t Qs[64 * 72];   // Q rows; later P
  __shared__ __align__(16) bf16_t Ks[64 * 72];   // K rows; later O epilogue
  __shared__ __align__(16) bf16_t VsT[64 * 70];  // V^T [dd][k]

  const int gidx = blockIdx.x;                   // 8*8*64 = 4096 groups
  const int r = gidx & 63, h = (gidx >> 6) & 7, b = gidx >> 9;
  const int tid = threadIdx.x, lane = tid & 63, w = tid >> 6;
  const int quad = lane >> 4, r16 = lane & 15;
  const size_t row0 = (size_t)b * 4096 + (size_t)r * 64;   // first token row of group

  // ---- stage: thread t -> (row=t>>2, 16-elem seg=t&3)
  {
    const int row = tid >> 2, seg = tid & 3;
    const bf16_t* gp = QKV + (row0 + row) * 1536 + h * 64 + seg * 16;
    *(bf16x8*)&Qs[row * 72 + seg * 16]     = *(const bf16x8*)&gp[0];
    *(bf16x8*)&Qs[row * 72 + seg * 16 + 8] = *(const bf16x8*)&gp[8];
    *(bf16x8*)&Ks[row * 72 + seg * 16]     = *(const bf16x8*)&gp[512];
    *(bf16x8*)&Ks[row * 72 + seg * 16 + 8] = *(const bf16x8*)&gp[520];
    bf16x8 v0 = *(const bf16x8*)&gp[1024];
    bf16x8 v1 = *(const bf16x8*)&gp[1032];
#pragma unroll
    for (int e = 0; e < 8; ++e) {
      VsT[(seg * 16 + e) * 70 + row]     = v0[e];   // VsT[dd][k=row]
      VsT[(seg * 16 + 8 + e) * 70 + row] = v1[e];
    }
  }
  __syncthreads();

  // ---- S = (Q K^T); wave w owns score rows [16w, 16w+16)
  f32x4 sacc[4] = {};
#pragma unroll
  for (int ks = 0; ks < 2; ++ks) {
    bf16x8 aq = *(const bf16x8*)&Qs[(w * 16 + r16) * 72 + ks * 32 + quad * 8];
#pragma unroll
    for (int nj = 0; nj < 4; ++nj) {
      bf16x8 bk = *(const bf16x8*)&Ks[(nj * 16 + r16) * 72 + ks * 32 + quad * 8];
      sacc[nj] = __builtin_amdgcn_mfma_f32_16x16x32_bf16(aq, bk, sacc[nj], 0, 0, 0);
    }
  }

  // ---- in-register softmax. Lane holds S[row=w*16+quad*4+rg][col=nj*16+r16]*0.125.
  float ex[4][4];                      // [nj][rg]
  float sm[4];
#pragma unroll
  for (int rg = 0; rg < 4; ++rg) {
    float m = -3.0e38f;
#pragma unroll
    for (int nj = 0; nj < 4; ++nj) {
      ex[nj][rg] = sacc[nj][rg] * 0.125f;
      m = fmaxf(m, ex[nj][rg]);
    }
    m = fmaxf(m, __shfl_xor(m, 1));
    m = fmaxf(m, __shfl_xor(m, 2));
    m = fmaxf(m, __shfl_xor(m, 4));
    m = fmaxf(m, __shfl_xor(m, 8));
    float s = 0.f;
#pragma unroll
    for (int nj = 0; nj < 4; ++nj) { ex[nj][rg] = __expf(ex[nj][rg] - m); s += ex[nj][rg]; }
    s += __shfl_xor(s, 1);
    s += __shfl_xor(s, 2);
    s += __shfl_xor(s, 4);
    s += __shfl_xor(s, 8);
    sm[rg] = 2.0f / s;                 // x2: row+col branches identical
  }

  __syncthreads();                     // all waves done reading Qs
#pragma unroll
  for (int nj = 0; nj < 4; ++nj)
#pragma unroll
    for (int rg = 0; rg < 4; ++rg)
      Qs[(w * 16 + quad * 4 + rg) * 72 + nj * 16 + r16] = f2bf(ex[nj][rg] * sm[rg]);
  __syncthreads();

  // ---- O = P @ V via VsT (b128 b-frags)
  f32x4 oacc[4] = {};
#pragma unroll
  for (int ks = 0; ks < 2; ++ks) {
    bf16x8 ap = *(const bf16x8*)&Qs[(w * 16 + r16) * 72 + ks * 32 + quad * 8];
#pragma unroll
    for (int nj = 0; nj < 4; ++nj) {
      bf16x8 bv = *(const bf16x8*)&VsT[(nj * 16 + r16) * 70 + ks * 32 + quad * 8];
      oacc[nj] = __builtin_amdgcn_mfma_f32_16x16x32_bf16(ap, bv, oacc[nj], 0, 0, 0);
    }
  }

  // ---- epilogue through LDS (reuse Ks, pitch 72) -> 128B-contiguous stores
  {
    bf16_t* Es = Ks;
#pragma unroll
    for (int nj = 0; nj < 4; ++nj)
#pragma unroll
      for (int rg = 0; rg < 4; ++rg)
        Es[(w * 16 + quad * 4 + rg) * 72 + nj * 16 + r16] = f2bf(oacc[nj][rg]);
    __syncthreads();
    const size_t obase = row0 * 512 + (size_t)h * 64;   // Aout [32768][512]
#pragma unroll
    for (int rd = 0; rd < 2; ++rd) {
      const int row = rd * 32 + (tid >> 3);
      const int col = (tid & 7) * 8;
      *(bf16x8*)&Aout[obase + (size_t)row * 512 + col] = *(const bf16x8*)&Es[row * 72 + col];
    }
  }
}

// ---------------------------------------------------------------------------
extern "C" void kernel_launch(void* const* d_in, const int* in_sizes, int n_in,
                              void* d_out, int out_size, void* d_ws, size_t ws_size,
                              hipStream_t stream)
{
  const float* x  = (const float*)d_in[0];
  const float* Wq = (const float*)d_in[1];
  const float* Wk = (const float*)d_in[2];
  const float* Wv = (const float*)d_in[3];
  const float* Wo = (const float*)d_in[4];
  const float* bo = (const float*)d_in[5];

  bf16_t* ws = (bf16_t*)d_ws;
  // workspace (bf16 elems):
  //   WT  : 4 x 262144   @ 0           (Wq|Wk|Wv rows 0..1535 stacked, then Wo)
  //   xbf : 16,777,216   @ 1,048,576   (dead after QKV GEMM; Ab aliases it)
  //   QKV : 50,331,648   @ 17,825,792  ([32768][1536] interleaved Q|K|V)
  // total 68,157,440 elems = 136,314,880 bytes
  bf16_t* WT  = ws;
  bf16_t* xbf = ws + 1048576;
  bf16_t* QKV = xbf + 16777216;
  bf16_t* Ab  = xbf;

  prep<<<dim3(17408), 256, 0, stream>>>(x, Wq, Wk, Wv, Wo, xbf, WT);

  // fused QKV projection: B = stacked WTq|WTk|WTv (1536 rows), 128x128 tiles
  gemm128<false><<<dim3(12, 256), 256, 0, stream>>>(xbf, WT, QKV, nullptr, 1536);

  cc_attn<<<dim3(4096), 256, 0, stream>>>(QKV, Ab);

  gemm128<true><<<dim3(4, 256), 256, 0, stream>>>(Ab, WT + 786432, d_out, bo, 512);
}